// Round 3
// baseline (393.045 us; speedup 1.0000x reference)
//
#include <hip/hip_runtime.h>
#include <hip/hip_bf16.h>

#define V 50000
#define H 256
#define B 512

typedef __bf16 bf16x8 __attribute__((ext_vector_type(8)));
typedef float f32x4 __attribute__((ext_vector_type(4)));

__device__ __forceinline__ float tanh_fast(float x) {
    float a = __builtin_fabsf(x);
    float e = __expf(2.0f * a);                        // inf for large a -> r=1
    float r = fmaf(-2.0f, __builtin_amdgcn_rcpf(e + 1.0f), 1.0f);
    return __builtin_copysignf(r, x);
}

// ---------------- Kernel A: gather + h0@w_hh.T + GRU cell ----------------
// 256 blocks x 256 threads, 2 batches per block. Thread t owns gate index j=t.
__global__ __launch_bounds__(256) void gru_h1_kernel(
    const int* __restrict__ ids, const float* __restrict__ h0,
    const float* __restrict__ w_ih, const float* __restrict__ w_hh,
    const float* __restrict__ b_ih, const float* __restrict__ b_hh,
    float* __restrict__ h1_out, __bf16* __restrict__ h1b)
{
    __shared__ float h0s[2 * 256];
    const int t = threadIdx.x;
    const int b0 = blockIdx.x * 2;

#pragma unroll
    for (int i = 0; i < 2; i++)
        h0s[i * 256 + t] = h0[(b0 + i) * 256 + t];
    __syncthreads();

    const int j = t;

    // Scattered one-hot gathers issued FIRST: their ~900cyc HBM latency
    // overlaps the w_hh dot-product loop.
    int id[2];
    float gir[2], giz[2], gin[2];
#pragma unroll
    for (int m = 0; m < 2; m++) {
        id[m] = ids[b0 + m];
        gir[m] = w_ih[(size_t)j * V + id[m]];
        giz[m] = w_ih[(size_t)(H + j) * V + id[m]];
        gin[m] = w_ih[(size_t)(2 * H + j) * V + id[m]];
    }

    float ar[2] = {0.f, 0.f}, az[2] = {0.f, 0.f}, an[2] = {0.f, 0.f};
    const float* __restrict__ wr_p = w_hh + (size_t)j * H;
    const float* __restrict__ wz_p = w_hh + (size_t)(H + j) * H;
    const float* __restrict__ wn_p = w_hh + (size_t)(2 * H + j) * H;

#pragma unroll 4
    for (int k = 0; k < H; k += 4) {
        f32x4 wr = *(const f32x4*)(wr_p + k);
        f32x4 wz = *(const f32x4*)(wz_p + k);
        f32x4 wn = *(const f32x4*)(wn_p + k);
#pragma unroll
        for (int m = 0; m < 2; m++) {
            f32x4 h = *(const f32x4*)&h0s[m * 256 + k];  // LDS broadcast
#pragma unroll
            for (int u = 0; u < 4; u++) {
                ar[m] = fmaf(wr[u], h[u], ar[m]);
                az[m] = fmaf(wz[u], h[u], az[m]);
                an[m] = fmaf(wn[u], h[u], an[m]);
            }
        }
    }

    const float bir = b_ih[j], biz = b_ih[H + j], bin = b_ih[2 * H + j];
    const float bhr = b_hh[j], bhz = b_hh[H + j], bhn = b_hh[2 * H + j];

#pragma unroll
    for (int m = 0; m < 2; m++) {
        float r = 1.f / (1.f + __expf(-(gir[m] + bir + ar[m] + bhr)));
        float z = 1.f / (1.f + __expf(-(giz[m] + biz + az[m] + bhz)));
        float n = tanh_fast(gin[m] + bin + r * (an[m] + bhn));
        float h1 = (1.f - z) * n + z * h0s[m * 256 + j];
        h1_out[(b0 + m) * H + j] = h1;
        h1b[(b0 + m) * H + j] = (__bf16)h1;
    }
}

// ---------------- Kernel B: logits = tanh(h1 @ w_out.T + b_out) ----------
// BARRIER-FREE MFMA. Each wave privately owns a 16-row n-slab: B fragments
// go global->reg (fp32->bf16 cvt), A fragments come from L2-hot bf16 h1b.
// No LDS, no __syncthreads, pure dataflow -> latency hidden by 12 waves/CU.
// Swapped operands mfma(B,A,acc): D[n][m], lane(q,v16) reg r ->
//   n = slab + q*4 + r (4 consecutive -> dwordx4 stores), m = m0 + mi*16 + v16.
__global__ __launch_bounds__(256, 3) void logit_kernel(
    const __bf16* __restrict__ h1b, const float* __restrict__ w_out,
    const float* __restrict__ b_out, float* __restrict__ out)
{
    const int t = threadIdx.x;
    const int lane = t & 63;
    const int wave = t >> 6;
    const int q = lane >> 4;
    const int v16 = lane & 15;
    const int slab = blockIdx.x * 64 + wave * 16;  // this wave's 16 n-rows
    const int n_row = slab + v16;                  // B-fragment row
    const int m0 = blockIdx.y * 256;

    // B fragments for all 8 k-steps, held in regs (32 VGPR).
    bf16x8 bfr[8];
    {
        const float* bp = w_out + (size_t)n_row * H + q * 8;
        const bool valid = (n_row < V);
#pragma unroll
        for (int ks = 0; ks < 8; ks++) {
            f32x4 lo = valid ? *(const f32x4*)(bp + ks * 32)     : (f32x4){0.f,0.f,0.f,0.f};
            f32x4 hi = valid ? *(const f32x4*)(bp + ks * 32 + 4) : (f32x4){0.f,0.f,0.f,0.f};
            bf16x8 v;
            v[0] = (__bf16)lo[0]; v[1] = (__bf16)lo[1];
            v[2] = (__bf16)lo[2]; v[3] = (__bf16)lo[3];
            v[4] = (__bf16)hi[0]; v[5] = (__bf16)hi[1];
            v[6] = (__bf16)hi[2]; v[7] = (__bf16)hi[3];
            bfr[ks] = v;
        }
    }

    const __bf16* ap = h1b + (size_t)(m0 + v16) * H + q * 8;

    f32x4 acc[16];
#pragma unroll
    for (int mi = 0; mi < 16; mi++) acc[mi] = (f32x4){0.f, 0.f, 0.f, 0.f};

#pragma unroll
    for (int mi = 0; mi < 16; mi++) {
        bf16x8 a[8];
#pragma unroll
        for (int ks = 0; ks < 8; ks++)
            a[ks] = *(const bf16x8*)(ap + mi * 16 * H + ks * 32);
#pragma unroll
        for (int ks = 0; ks < 8; ks++)
            acc[mi] = __builtin_amdgcn_mfma_f32_16x16x32_bf16(
                bfr[ks], a[ks], acc[mi], 0, 0, 0);
    }

    // Epilogue: 4 consecutive n per lane -> dwordx4 stores. V%16==0 slabs.
    const int n_st = slab + q * 4;
    if (n_st < V) {
        f32x4 bo = *(const f32x4*)&b_out[n_st];
#pragma unroll
        for (int mi = 0; mi < 16; mi++) {
            f32x4 r;
#pragma unroll
            for (int u = 0; u < 4; u++)
                r[u] = tanh_fast(acc[mi][u] + bo[u]);
            *(f32x4*)&out[(size_t)(m0 + mi * 16 + v16) * V + n_st] = r;
        }
    }
}

extern "C" void kernel_launch(void* const* d_in, const int* in_sizes, int n_in,
                              void* d_out, int out_size, void* d_ws, size_t ws_size,
                              hipStream_t stream) {
    const int* ids = (const int*)d_in[0];
    const float* hidden = (const float*)d_in[1];
    const float* w_ih = (const float*)d_in[2];
    const float* w_hh = (const float*)d_in[3];
    const float* b_ih = (const float*)d_in[4];
    const float* b_hh = (const float*)d_in[5];
    const float* w_out = (const float*)d_in[6];
    const float* b_out = (const float*)d_in[7];

    float* out = (float*)d_out;
    float* h1_out = out + (size_t)B * V;
    __bf16* h1b = (__bf16*)d_ws;

    gru_h1_kernel<<<256, 256, 0, stream>>>(ids, hidden, w_ih, w_hh, b_ih, b_hh,
                                           h1_out, h1b);

    dim3 grid((V + 63) / 64, 2);  // x = n-slab(64), y = m-half(256)
    logit_kernel<<<grid, 256, 0, stream>>>(h1b, w_out, b_out, out);
}